// Round 5
// baseline (153.473 us; speedup 1.0000x reference)
//
#include <hip/hip_runtime.h>
#include <hip/hip_bf16.h>

typedef unsigned short u16;
typedef __attribute__((ext_vector_type(8))) short bf16x8;
typedef __attribute__((ext_vector_type(4))) float f32x4;

#define B_ 16
#define CIN 256
#define COUT 256
#define NPIX 4096
#define E_ 8
#define HP 66            // halo-padded width/height
#define PPIX (HP*HP)     // 4356 padded pixels per sample
#define KTOT 2304        // 9 * 256
#define NKT 36           // K-tiles of 64

__device__ __forceinline__ u16 f2bf(float f){
    union { float f; unsigned int u; } v; v.f = f;
    return (u16)((v.u + 0x7FFFu + ((v.u >> 16) & 1u)) >> 16);
}

__device__ __forceinline__ void gload(const u16* g, u16* l){
    __builtin_amdgcn_global_load_lds(
        (const __attribute__((address_space(1))) unsigned int*)g,
        (__attribute__((address_space(3))) unsigned int*)l, 16, 0, 0);
}

// -------- 0) zero halo borders of xt2 + zero pooled --------
__global__ void k_zero(u16* __restrict__ xt2, float* __restrict__ pooled){
    int gid = blockIdx.x*256 + threadIdx.x;
    if (gid < B_*CIN) pooled[gid] = 0.f;
    int u4 = gid & 31;
    int pl = gid >> 5;
    if (pl >= B_*260) return;
    int b = pl / 260;
    int pi = pl - b*260;
    int y, x;
    if (pi < 66)      { y = 0;  x = pi; }
    else if (pi < 132){ y = 65; x = pi - 66; }
    else { int q = pi - 132; y = 1 + (q >> 1); x = (q & 1) ? 65 : 0; }
    uint4 z = {0u,0u,0u,0u};
    *(uint4*)(xt2 + ((size_t)b*PPIX + y*HP + x)*CIN + u4*8) = z;
}

// -------- 1) transpose+convert x -> xt2[b][(y+1)*66+(x+1)][cin] bf16, fused pool --------
__global__ void k_xt(const float* __restrict__ x, u16* __restrict__ xt2,
                     float* __restrict__ pooled){
    __shared__ float tile[64][65];
    int bid = blockIdx.x;
    int b = bid >> 8, ct = (bid >> 6) & 3, pt = bid & 63;
    int c0 = ct*64, p0 = pt*64, t = threadIdx.x;
    #pragma unroll
    for (int iter = 0; iter < 4; ++iter){
        int idx = t*4 + iter*1024;
        int r = idx >> 6, c4 = idx & 63;
        float4 v = *(const float4*)(x + ((size_t)(b*CIN + c0 + r))*NPIX + p0 + c4);
        tile[r][c4+0] = v.x; tile[r][c4+1] = v.y; tile[r][c4+2] = v.z; tile[r][c4+3] = v.w;
        float rs = v.x + v.y + v.z + v.w;
        #pragma unroll
        for (int off = 1; off < 16; off <<= 1) rs += __shfl_xor(rs, off, 64);
        if ((t & 15) == 0) atomicAdd(&pooled[b*CIN + c0 + r], rs);
    }
    __syncthreads();
    #pragma unroll
    for (int iter = 0; iter < 4; ++iter){
        int idx = t*4 + iter*1024;
        int pr = idx >> 6, cc = idx & 63;
        ushort4 u;
        u.x = f2bf(tile[cc+0][pr]);
        u.y = f2bf(tile[cc+1][pr]);
        u.z = f2bf(tile[cc+2][pr]);
        u.w = f2bf(tile[cc+3][pr]);
        int p = p0 + pr;
        int yy = p >> 6, xx = p & 63;
        *(ushort4*)(xt2 + ((size_t)b*PPIX + (yy+1)*HP + (xx+1))*CIN + c0 + cc) = u;
    }
}

// -------- 2) routing + aggregated bias --------
__global__ void k_route(const float* __restrict__ pooled, const float* __restrict__ rw,
                        const float* __restrict__ rb, const float* __restrict__ bias,
                        float* __restrict__ routing, float* __restrict__ aggb)
{
    __shared__ float r_s[B_*E_];
    int t = threadIdx.x;
    if (t < B_*E_){
        int b = t >> 3, e = t & 7;
        float s = 0.f;
        const float* pp = pooled + b*CIN;
        const float* wp = rw + e*CIN;
        for (int i = 0; i < CIN; ++i) s += pp[i]*wp[i];
        s = s * (1.0f/(float)NPIX) + rb[e];
        float r = 1.0f/(1.0f + __expf(-s));
        routing[t] = r;
        r_s[t] = r;
    }
    __syncthreads();
    for (int idx = t; idx < B_*COUT; idx += 256){
        int b = idx >> 8, o = idx & 255;
        float s = 0.f;
        #pragma unroll
        for (int e = 0; e < E_; ++e) s += r_s[b*E_+e]*bias[e*COUT+o];
        aggb[idx] = s;
    }
}

// -------- 3) aggregated weights, LDS-coalesced read, layout [b][o][tap][cin] --------
__global__ void k_aggw(const float* __restrict__ weight, const float* __restrict__ routing,
                       u16* __restrict__ aggw)
{
    __shared__ float wls[E_][2304];
    __shared__ float r_s[B_*E_];
    int o = blockIdx.x, t = threadIdx.x;
    if (t < B_*E_) r_s[t] = routing[t];
    #pragma unroll
    for (int e = 0; e < E_; ++e){
        const float4* src = (const float4*)(weight + ((size_t)(e*COUT + o))*2304);
        float4* dst = (float4*)wls[e];
        #pragma unroll
        for (int i = 0; i < 3; ++i){
            int idx = t + i*256;
            if (idx < 576) dst[idx] = src[idx];
        }
    }
    __syncthreads();
    float w[E_][9];
    #pragma unroll
    for (int e = 0; e < E_; ++e)
        #pragma unroll
        for (int tp = 0; tp < 9; ++tp) w[e][tp] = wls[e][t*9 + tp];
    for (int b = 0; b < B_; ++b){
        float acc[9];
        #pragma unroll
        for (int tp = 0; tp < 9; ++tp) acc[tp] = 0.f;
        #pragma unroll
        for (int e = 0; e < E_; ++e){
            float r = r_s[b*E_+e];
            #pragma unroll
            for (int tp = 0; tp < 9; ++tp) acc[tp] += r*w[e][tp];
        }
        #pragma unroll
        for (int tp = 0; tp < 9; ++tp)
            aggw[(((size_t)(b*COUT + o))*9 + tp)*CIN + t] = f2bf(acc[tp]);
    }
}

// -------- 4) 128x256-tile conv: 3-buffer circular pipeline, counted vmcnt --------
__global__ __launch_bounds__(512, 1) void k_conv(
    const u16* __restrict__ aggw, const u16* __restrict__ xt2,
    const float* __restrict__ aggb, float* __restrict__ out)
{
    // 144 KB LDS: 3 bufs x (A 128x64 16KB + B 256x64 32KB) bf16
    __shared__ __align__(16) u16 lds[73728];

    int orig = blockIdx.x;
    int bid = (orig & 7)*64 + (orig >> 3);   // bijective XCD swizzle (512 % 8 == 0)

    int b  = bid >> 5;
    int mt = (bid >> 4) & 1;
    int nt = bid & 15;
    int m0 = mt << 7;
    int y0 = nt << 2;

    int t = threadIdx.x;
    int lane = t & 63;
    int w = t >> 6;
    int wm = (w >> 2) << 6;      // 0 / 64
    int wn = (w & 3) << 6;       // 0 / 64 / 128 / 192
    int l16 = lane & 15;
    int kh4 = lane >> 4;

    int tr = t >> 3;             // staging row 0..63
    int sc = (t & 7) ^ (tr & 7); // pre-swizzled source chunk

    const u16* aA = aggw + (size_t)b*COUT*9*CIN + (size_t)(m0 + tr)*KTOT + sc*8;
    const u16* bB = xt2 + ((size_t)b*PPIX + (size_t)y0*HP + tr)*CIN + sc*8;

    int ck0 = ((kh4    ) ^ (l16 & 7)) * 8;
    int ck1 = ((kh4 | 4) ^ (l16 & 7)) * 8;

    f32x4 acc[4][4];
    #pragma unroll
    for (int i = 0; i < 4; ++i)
        #pragma unroll
        for (int j = 0; j < 4; ++j){
            f32x4 z = {0.f,0.f,0.f,0.f};
            acc[i][j] = z;
        }

    auto stage = [&](int kt, int bufn){
        int tap = kt >> 2;
        int c0  = (kt & 3) << 6;
        int kh  = tap / 3, kw = tap - kh*3;
        const u16* a0 = aA + tap*CIN + c0;
        const u16* b0 = bB + kw*CIN + c0;
        u16* dA = lds + bufn*24576 + w*512;
        u16* dB = dA + 8192;
        gload(a0, dA);
        gload(a0 + (size_t)64*KTOT, dA + 4096);
        #pragma unroll
        for (int i = 0; i < 4; ++i)
            gload(b0 + (size_t)(i + kh)*HP*CIN, dB + i*4096);
    };

    stage(0, 0);                 // 6 loads
    stage(1, 1);                 // 6 loads -> 12 in flight

    int bc = 0;
    for (int kt = 0; kt < NKT; ++kt){
        // counted wait: tile kt's 6 loads are the oldest; keep kt+1's in flight
        if (kt + 1 < NKT) asm volatile("s_waitcnt vmcnt(6)" ::: "memory");
        else              asm volatile("s_waitcnt vmcnt(0)" ::: "memory");
        __builtin_amdgcn_s_barrier();      // all waves: tile kt staged; buf (kt+2)%3 free
        asm volatile("" ::: "memory");

        if (kt + 2 < NKT){
            int b2 = bc + 2; if (b2 >= 3) b2 -= 3;
            stage(kt + 2, b2);
        }

        const u16* LA = lds + bc*24576;
        const u16* LB = LA + 8192;

        bf16x8 af[4][2], bfr[4][2];
        #pragma unroll
        for (int mf = 0; mf < 4; ++mf){
            int ro = (wm + mf*16 + l16) * 64;
            af[mf][0] = *(const bf16x8*)(LA + ro + ck0);
            af[mf][1] = *(const bf16x8*)(LA + ro + ck1);
        }
        #pragma unroll
        for (int nf = 0; nf < 4; ++nf){
            int ro = (wn + nf*16 + l16) * 64;
            bfr[nf][0] = *(const bf16x8*)(LB + ro + ck0);
            bfr[nf][1] = *(const bf16x8*)(LB + ro + ck1);
        }

        asm volatile("s_waitcnt lgkmcnt(0)" ::: "memory");
        __builtin_amdgcn_sched_barrier(0);   // rule #18: don't hoist MFMA above the wait

        __builtin_amdgcn_s_setprio(1);
        #pragma unroll
        for (int mf = 0; mf < 4; ++mf)
            #pragma unroll
            for (int nf = 0; nf < 4; ++nf){
                acc[mf][nf] = __builtin_amdgcn_mfma_f32_16x16x32_bf16(
                    af[mf][0], bfr[nf][0], acc[mf][nf], 0, 0, 0);
                acc[mf][nf] = __builtin_amdgcn_mfma_f32_16x16x32_bf16(
                    af[mf][1], bfr[nf][1], acc[mf][nf], 0, 0, 0);
            }
        __builtin_amdgcn_s_setprio(0);

        bc = (bc == 2) ? 0 : bc + 1;
    }

    const float* ab = aggb + b*COUT + m0;
    float* outp = out + ((size_t)(b*COUT + m0))*NPIX + nt*256;
    #pragma unroll
    for (int mf = 0; mf < 4; ++mf){
        #pragma unroll
        for (int v = 0; v < 4; ++v){
            int r = wm + mf*16 + kh4*4 + v;
            float bias_r = ab[r];
            float* orow = outp + (size_t)r*NPIX;
            #pragma unroll
            for (int nf = 0; nf < 4; ++nf)
                orow[wn + nf*16 + l16] = acc[mf][nf][v] + bias_r;
        }
    }
}

extern "C" void kernel_launch(void* const* d_in, const int* in_sizes, int n_in,
                              void* d_out, int out_size, void* d_ws, size_t ws_size,
                              hipStream_t stream)
{
    const float* x      = (const float*)d_in[0];
    const float* weight = (const float*)d_in[1];
    const float* bias   = (const float*)d_in[2];
    const float* rw     = (const float*)d_in[3];
    const float* rb     = (const float*)d_in[4];
    float* out = (float*)d_out;

    char* ws = (char*)d_ws;
    u16*   aggw    = (u16*)(ws);                          // 18,874,368 B
    u16*   xt2     = (u16*)(ws + 18874368);               // 35,684,352 B (halo 66x66)
    float* pooled  = (float*)(ws + 54558720);             // 16 KB
    float* routing = (float*)(ws + 54558720 + 16384);     // 512 B
    float* aggb    = (float*)(ws + 54558720 + 16384 + 512); // 16 KB

    k_zero <<<520,  256, 0, stream>>>(xt2, pooled);
    k_xt   <<<4096, 256, 0, stream>>>(x, xt2, pooled);
    k_route<<<1,    256, 0, stream>>>(pooled, rw, rb, bias, routing, aggb);
    k_aggw <<<COUT, 256, 0, stream>>>(weight, routing, aggw);
    k_conv <<<512,  512, 0, stream>>>(aggw, xt2, aggb, out);
}

// Round 6
// 151.402 us; speedup vs baseline: 1.0137x; 1.0137x over previous
//
#include <hip/hip_runtime.h>
#include <hip/hip_bf16.h>

typedef unsigned short u16;
typedef __attribute__((ext_vector_type(8))) short bf16x8;
typedef __attribute__((ext_vector_type(4))) float f32x4;

#define B_ 16
#define CIN 256
#define COUT 256
#define NPIX 4096
#define E_ 8
#define HP 66            // halo-padded width/height
#define PPIX (HP*HP)     // 4356 padded pixels per sample
#define KTOT 2304        // 9 * 256
#define NKT2 72          // K-tiles of 32

__device__ __forceinline__ u16 f2bf(float f){
    union { float f; unsigned int u; } v; v.f = f;
    return (u16)((v.u + 0x7FFFu + ((v.u >> 16) & 1u)) >> 16);
}

__device__ __forceinline__ void gload(const u16* g, u16* l){
    __builtin_amdgcn_global_load_lds(
        (const __attribute__((address_space(1))) unsigned int*)g,
        (__attribute__((address_space(3))) unsigned int*)l, 16, 0, 0);
}

// -------- 0) zero halo borders of xt2 + zero pooled --------
__global__ void k_zero(u16* __restrict__ xt2, float* __restrict__ pooled){
    int gid = blockIdx.x*256 + threadIdx.x;
    if (gid < B_*CIN) pooled[gid] = 0.f;
    int u4 = gid & 31;
    int pl = gid >> 5;
    if (pl >= B_*260) return;
    int b = pl / 260;
    int pi = pl - b*260;
    int y, x;
    if (pi < 66)      { y = 0;  x = pi; }
    else if (pi < 132){ y = 65; x = pi - 66; }
    else { int q = pi - 132; y = 1 + (q >> 1); x = (q & 1) ? 65 : 0; }
    uint4 z = {0u,0u,0u,0u};
    *(uint4*)(xt2 + ((size_t)b*PPIX + y*HP + x)*CIN + u4*8) = z;
}

// -------- 1) transpose+convert x -> xt2[b][(y+1)*66+(x+1)][cin] bf16, fused pool --------
__global__ void k_xt(const float* __restrict__ x, u16* __restrict__ xt2,
                     float* __restrict__ pooled){
    __shared__ float tile[64][65];
    int bid = blockIdx.x;
    int b = bid >> 8, ct = (bid >> 6) & 3, pt = bid & 63;
    int c0 = ct*64, p0 = pt*64, t = threadIdx.x;
    #pragma unroll
    for (int iter = 0; iter < 4; ++iter){
        int idx = t*4 + iter*1024;
        int r = idx >> 6, c4 = idx & 63;
        float4 v = *(const float4*)(x + ((size_t)(b*CIN + c0 + r))*NPIX + p0 + c4);
        tile[r][c4+0] = v.x; tile[r][c4+1] = v.y; tile[r][c4+2] = v.z; tile[r][c4+3] = v.w;
        float rs = v.x + v.y + v.z + v.w;
        #pragma unroll
        for (int off = 1; off < 16; off <<= 1) rs += __shfl_xor(rs, off, 64);
        if ((t & 15) == 0) atomicAdd(&pooled[b*CIN + c0 + r], rs);
    }
    __syncthreads();
    #pragma unroll
    for (int iter = 0; iter < 4; ++iter){
        int idx = t*4 + iter*1024;
        int pr = idx >> 6, cc = idx & 63;
        ushort4 u;
        u.x = f2bf(tile[cc+0][pr]);
        u.y = f2bf(tile[cc+1][pr]);
        u.z = f2bf(tile[cc+2][pr]);
        u.w = f2bf(tile[cc+3][pr]);
        int p = p0 + pr;
        int yy = p >> 6, xx = p & 63;
        *(ushort4*)(xt2 + ((size_t)b*PPIX + (yy+1)*HP + (xx+1))*CIN + c0 + cc) = u;
    }
}

// -------- 2) routing + aggregated bias --------
__global__ void k_route(const float* __restrict__ pooled, const float* __restrict__ rw,
                        const float* __restrict__ rb, const float* __restrict__ bias,
                        float* __restrict__ routing, float* __restrict__ aggb)
{
    __shared__ float r_s[B_*E_];
    int t = threadIdx.x;
    if (t < B_*E_){
        int b = t >> 3, e = t & 7;
        float s = 0.f;
        const float* pp = pooled + b*CIN;
        const float* wp = rw + e*CIN;
        for (int i = 0; i < CIN; ++i) s += pp[i]*wp[i];
        s = s * (1.0f/(float)NPIX) + rb[e];
        float r = 1.0f/(1.0f + __expf(-s));
        routing[t] = r;
        r_s[t] = r;
    }
    __syncthreads();
    for (int idx = t; idx < B_*COUT; idx += 256){
        int b = idx >> 8, o = idx & 255;
        float s = 0.f;
        #pragma unroll
        for (int e = 0; e < E_; ++e) s += r_s[b*E_+e]*bias[e*COUT+o];
        aggb[idx] = s;
    }
}

// -------- 3) aggregated weights, LDS-coalesced read, layout [b][o][tap][cin] --------
__global__ void k_aggw(const float* __restrict__ weight, const float* __restrict__ routing,
                       u16* __restrict__ aggw)
{
    __shared__ float wls[E_][2304];
    __shared__ float r_s[B_*E_];
    int o = blockIdx.x, t = threadIdx.x;
    if (t < B_*E_) r_s[t] = routing[t];
    #pragma unroll
    for (int e = 0; e < E_; ++e){
        const float4* src = (const float4*)(weight + ((size_t)(e*COUT + o))*2304);
        float4* dst = (float4*)wls[e];
        #pragma unroll
        for (int i = 0; i < 3; ++i){
            int idx = t + i*256;
            if (idx < 576) dst[idx] = src[idx];
        }
    }
    __syncthreads();
    float w[E_][9];
    #pragma unroll
    for (int e = 0; e < E_; ++e)
        #pragma unroll
        for (int tp = 0; tp < 9; ++tp) w[e][tp] = wls[e][t*9 + tp];
    for (int b = 0; b < B_; ++b){
        float acc[9];
        #pragma unroll
        for (int tp = 0; tp < 9; ++tp) acc[tp] = 0.f;
        #pragma unroll
        for (int e = 0; e < E_; ++e){
            float r = r_s[b*E_+e];
            #pragma unroll
            for (int tp = 0; tp < 9; ++tp) acc[tp] += r*w[e][tp];
        }
        #pragma unroll
        for (int tp = 0; tp < 9; ++tp)
            aggw[(((size_t)(b*COUT + o))*9 + tp)*CIN + t] = f2bf(acc[tp]);
    }
}

// -------- 4) 256x256 tile, BK=32, 4-buffer pipeline 3 tiles ahead, counted vmcnt --------
__global__ __launch_bounds__(512, 1) void k_conv(
    const u16* __restrict__ aggw, const u16* __restrict__ xt2,
    const float* __restrict__ aggb, float* __restrict__ out)
{
    // 128 KB: 4 bufs x (A 256x32 16KB + B 256x32 16KB), linear (64B rows: conflict-free)
    __shared__ __align__(16) u16 lds[65536];

    int orig = blockIdx.x;
    int bid = (orig & 7)*32 + (orig >> 3);   // bijective XCD swizzle (256 % 8 == 0)

    int b  = bid >> 4;
    int nt = bid & 15;
    int y0 = nt << 2;

    int t = threadIdx.x;
    int lane = t & 63;
    int w = t >> 6;
    int wm = (w >> 2) << 7;      // 0 / 128
    int wn = (w & 3) << 6;       // 0 / 64 / 128 / 192
    int l16 = lane & 15;
    int kh4 = lane >> 4;         // k-chunk group 0..3

    // staging: thread t covers LDS 16B slot t of each 8KB region
    int sr  = t >> 2;            // row 0..127 within half-region
    int sch = (t & 3) << 3;      // k-chunk offset (u16)

    const u16* aS = aggw + (size_t)b*COUT*9*CIN + (size_t)sr*(9*CIN) + sch;
    const u16* bS = xt2 + ((size_t)b*PPIX + (size_t)(y0 + (sr >> 6))*HP + (sr & 63))*CIN + sch;

    f32x4 acc[8][4];
    #pragma unroll
    for (int i = 0; i < 8; ++i)
        #pragma unroll
        for (int j = 0; j < 4; ++j){
            f32x4 z = {0.f,0.f,0.f,0.f};
            acc[i][j] = z;
        }

    auto stage = [&](int kt, int bufn){
        int tap = kt >> 3;
        int c0  = (kt & 7) << 5;
        int kh  = tap / 3, kw = tap - kh*3;
        const u16* a0 = aS + tap*CIN + c0;
        const u16* b0 = bS + (kh*HP + kw)*CIN + c0;
        u16* base = lds + bufn*16384 + w*512;
        gload(a0, base);
        gload(a0 + (size_t)128*9*CIN, base + 4096);
        gload(b0, base + 8192);
        gload(b0 + (size_t)2*HP*CIN, base + 12288);
    };

    stage(0, 0);
    stage(1, 1);
    stage(2, 2);                 // 12 loads in flight

    for (int kt = 0; kt < NKT2; ++kt){
        // retire tile kt's 4 loads (oldest); keep kt+1, kt+2 (and kt+3 later) in flight
        if (kt < NKT2-2)       asm volatile("s_waitcnt vmcnt(8)" ::: "memory");
        else if (kt == NKT2-2) asm volatile("s_waitcnt vmcnt(4)" ::: "memory");
        else                   asm volatile("s_waitcnt vmcnt(0)" ::: "memory");
        __builtin_amdgcn_s_barrier();    // all waves' tile-kt loads retired; buf[(kt-1)&3] readers done

        int bc = kt & 3;
        const u16* LA = lds + bc*16384;
        const u16* LB = LA + 8192;

        bf16x8 af[8], bfv[4];
        #pragma unroll
        for (int mf = 0; mf < 8; ++mf)
            af[mf] = *(const bf16x8*)(LA + (wm + mf*16 + l16)*32 + kh4*8);
        #pragma unroll
        for (int nf = 0; nf < 4; ++nf)
            bfv[nf] = *(const bf16x8*)(LB + (wn + nf*16 + l16)*32 + kh4*8);

        if (kt + 3 < NKT2) stage(kt + 3, (kt + 3) & 3);

        asm volatile("s_waitcnt lgkmcnt(0)" ::: "memory");
        __builtin_amdgcn_sched_barrier(0);   // rule #18

        __builtin_amdgcn_s_setprio(1);
        #pragma unroll
        for (int mf = 0; mf < 8; ++mf)
            #pragma unroll
            for (int nf = 0; nf < 4; ++nf)
                acc[mf][nf] = __builtin_amdgcn_mfma_f32_16x16x32_bf16(
                    af[mf], bfv[nf], acc[mf][nf], 0, 0, 0);
        __builtin_amdgcn_s_setprio(0);
    }

    const float* ab = aggb + b*COUT;
    float* outp = out + ((size_t)b*COUT)*NPIX + nt*256;
    #pragma unroll
    for (int mf = 0; mf < 8; ++mf){
        #pragma unroll
        for (int v = 0; v < 4; ++v){
            int r = wm + mf*16 + kh4*4 + v;
            float bias_r = ab[r];
            float* orow = outp + (size_t)r*NPIX;
            #pragma unroll
            for (int nf = 0; nf < 4; ++nf)
                orow[wn + nf*16 + l16] = acc[mf][nf][v] + bias_r;
        }
    }
}

extern "C" void kernel_launch(void* const* d_in, const int* in_sizes, int n_in,
                              void* d_out, int out_size, void* d_ws, size_t ws_size,
                              hipStream_t stream)
{
    const float* x      = (const float*)d_in[0];
    const float* weight = (const float*)d_in[1];
    const float* bias   = (const float*)d_in[2];
    const float* rw     = (const float*)d_in[3];
    const float* rb     = (const float*)d_in[4];
    float* out = (float*)d_out;

    char* ws = (char*)d_ws;
    u16*   aggw    = (u16*)(ws);                          // 18,874,368 B
    u16*   xt2     = (u16*)(ws + 18874368);               // 35,684,352 B (halo 66x66)
    float* pooled  = (float*)(ws + 54558720);             // 16 KB
    float* routing = (float*)(ws + 54558720 + 16384);     // 512 B
    float* aggb    = (float*)(ws + 54558720 + 16384 + 512); // 16 KB

    k_zero <<<520,  256, 0, stream>>>(xt2, pooled);
    k_xt   <<<4096, 256, 0, stream>>>(x, xt2, pooled);
    k_route<<<1,    256, 0, stream>>>(pooled, rw, rb, bias, routing, aggb);
    k_aggw <<<COUT, 256, 0, stream>>>(weight, routing, aggw);
    k_conv <<<256,  512, 0, stream>>>(aggw, xt2, aggb, out);
}

// Round 7
// 147.997 us; speedup vs baseline: 1.0370x; 1.0230x over previous
//
#include <hip/hip_runtime.h>
#include <hip/hip_bf16.h>

typedef unsigned short u16;
typedef __attribute__((ext_vector_type(8))) short bf16x8;
typedef __attribute__((ext_vector_type(4))) float f32x4;

#define B_ 16
#define CIN 256
#define COUT 256
#define NPIX 4096
#define E_ 8
#define HP 66            // halo-padded width/height
#define PPIX (HP*HP)     // 4356 padded pixels per sample
#define KTOT 2304        // 9 * 256
#define NKT2 72          // K-tiles of 32

__device__ __forceinline__ u16 f2bf(float f){
    union { float f; unsigned int u; } v; v.f = f;
    return (u16)((v.u + 0x7FFFu + ((v.u >> 16) & 1u)) >> 16);
}

__device__ __forceinline__ void gload(const u16* g, u16* l){
    __builtin_amdgcn_global_load_lds(
        (const __attribute__((address_space(1))) unsigned int*)g,
        (__attribute__((address_space(3))) unsigned int*)l, 16, 0, 0);
}

// -------- 0) zero halo borders of xt2 + zero pooled --------
__global__ void k_zero(u16* __restrict__ xt2, float* __restrict__ pooled){
    int gid = blockIdx.x*256 + threadIdx.x;
    if (gid < B_*CIN) pooled[gid] = 0.f;
    int u4 = gid & 31;
    int pl = gid >> 5;
    if (pl >= B_*260) return;
    int b = pl / 260;
    int pi = pl - b*260;
    int y, x;
    if (pi < 66)      { y = 0;  x = pi; }
    else if (pi < 132){ y = 65; x = pi - 66; }
    else { int q = pi - 132; y = 1 + (q >> 1); x = (q & 1) ? 65 : 0; }
    uint4 z = {0u,0u,0u,0u};
    *(uint4*)(xt2 + ((size_t)b*PPIX + y*HP + x)*CIN + u4*8) = z;
}

// -------- 1) transpose+convert x -> xt2[b][(y+1)*66+(x+1)][cin] bf16, fused pool --------
__global__ void k_xt(const float* __restrict__ x, u16* __restrict__ xt2,
                     float* __restrict__ pooled){
    __shared__ float tile[64][65];
    int bid = blockIdx.x;
    int b = bid >> 8, ct = (bid >> 6) & 3, pt = bid & 63;
    int c0 = ct*64, p0 = pt*64, t = threadIdx.x;
    #pragma unroll
    for (int iter = 0; iter < 4; ++iter){
        int idx = t*4 + iter*1024;
        int r = idx >> 6, c4 = idx & 63;
        float4 v = *(const float4*)(x + ((size_t)(b*CIN + c0 + r))*NPIX + p0 + c4);
        tile[r][c4+0] = v.x; tile[r][c4+1] = v.y; tile[r][c4+2] = v.z; tile[r][c4+3] = v.w;
        float rs = v.x + v.y + v.z + v.w;
        #pragma unroll
        for (int off = 1; off < 16; off <<= 1) rs += __shfl_xor(rs, off, 64);
        if ((t & 15) == 0) atomicAdd(&pooled[b*CIN + c0 + r], rs);
    }
    __syncthreads();
    #pragma unroll
    for (int iter = 0; iter < 4; ++iter){
        int idx = t*4 + iter*1024;
        int pr = idx >> 6, cc = idx & 63;
        ushort4 u;
        u.x = f2bf(tile[cc+0][pr]);
        u.y = f2bf(tile[cc+1][pr]);
        u.z = f2bf(tile[cc+2][pr]);
        u.w = f2bf(tile[cc+3][pr]);
        int p = p0 + pr;
        int yy = p >> 6, xx = p & 63;
        *(ushort4*)(xt2 + ((size_t)b*PPIX + (yy+1)*HP + (xx+1))*CIN + c0 + cc) = u;
    }
}

// -------- 2) aggregated weights + fused routing + aggregated bias --------
__global__ void k_aggw(const float* __restrict__ weight, const float* __restrict__ pooled,
                       const float* __restrict__ rw, const float* __restrict__ rb,
                       const float* __restrict__ bias,
                       u16* __restrict__ aggw, float* __restrict__ aggb)
{
    __shared__ float wls[E_][2304];
    __shared__ float r_s[B_*E_];
    int o = blockIdx.x, t = threadIdx.x;

    // routing recomputed per block (cheap; pooled/rw are L2-resident)
    if (t < B_*E_){
        int b = t >> 3, e = t & 7;
        const float4* pp = (const float4*)(pooled + b*CIN);
        const float4* wp = (const float4*)(rw + e*CIN);
        float s = 0.f;
        #pragma unroll
        for (int i = 0; i < 64; ++i){
            float4 a = pp[i], c = wp[i];
            s += a.x*c.x + a.y*c.y + a.z*c.z + a.w*c.w;
        }
        s = s * (1.0f/(float)NPIX) + rb[e];
        r_s[t] = 1.0f/(1.0f + __expf(-s));
    }
    #pragma unroll
    for (int e = 0; e < E_; ++e){
        const float4* src = (const float4*)(weight + ((size_t)(e*COUT + o))*2304);
        float4* dst = (float4*)wls[e];
        #pragma unroll
        for (int i = 0; i < 3; ++i){
            int idx = t + i*256;
            if (idx < 576) dst[idx] = src[idx];
        }
    }
    __syncthreads();

    if (t < B_){
        float s = 0.f;
        #pragma unroll
        for (int e = 0; e < E_; ++e) s += r_s[t*E_+e]*bias[e*COUT+o];
        aggb[t*COUT + o] = s;
    }

    float w[E_][9];
    #pragma unroll
    for (int e = 0; e < E_; ++e)
        #pragma unroll
        for (int tp = 0; tp < 9; ++tp) w[e][tp] = wls[e][t*9 + tp];
    for (int b = 0; b < B_; ++b){
        float acc[9];
        #pragma unroll
        for (int tp = 0; tp < 9; ++tp) acc[tp] = 0.f;
        #pragma unroll
        for (int e = 0; e < E_; ++e){
            float r = r_s[b*E_+e];
            #pragma unroll
            for (int tp = 0; tp < 9; ++tp) acc[tp] += r*w[e][tp];
        }
        #pragma unroll
        for (int tp = 0; tp < 9; ++tp)
            aggw[(((size_t)(b*COUT + o))*9 + tp)*CIN + t] = f2bf(acc[tp]);
    }
}

// -------- 3) 256x256 tile, BK=32, 4-buffer pipeline, counted vmcnt, 2-way swizzle --------
__global__ __launch_bounds__(512, 1) void k_conv(
    const u16* __restrict__ aggw, const u16* __restrict__ xt2,
    const float* __restrict__ aggb, float* __restrict__ out)
{
    // 128 KB: 4 bufs x (A 256x32 16KB + B 256x32 16KB)
    // swizzle: LDS slot (row, cs) holds logical chunk cs ^ ((row>>1)&3)
    __shared__ __align__(16) u16 lds[65536];

    int orig = blockIdx.x;
    int bid = (orig & 7)*32 + (orig >> 3);   // bijective XCD swizzle (256 % 8 == 0)

    int b  = bid >> 4;
    int nt = bid & 15;
    int y0 = nt << 2;

    int t = threadIdx.x;
    int lane = t & 63;
    int w = t >> 6;
    int wm = (w >> 2) << 7;      // 0 / 128
    int wn = (w & 3) << 6;       // 0 / 64 / 128 / 192
    int l16 = lane & 15;
    int kh4 = lane >> 4;         // logical k-chunk 0..3

    // read-side swizzled chunk offset (constant per lane: row bits 1-2 == l16 bits 1-2)
    int ck = ((kh4 ^ ((l16 >> 1) & 3)) << 3);

    // staging: thread t covers LDS slot (sr, t&3); fetch logical chunk (t&3)^((sr>>1)&3)
    int sr  = t >> 2;            // row 0..127 within half-region
    int lc8 = (((t & 3) ^ ((sr >> 1) & 3)) << 3);

    const u16* aS = aggw + (size_t)b*COUT*9*CIN + (size_t)sr*(9*CIN) + lc8;
    const u16* bS = xt2 + ((size_t)b*PPIX + (size_t)(y0 + (sr >> 6))*HP + (sr & 63))*CIN + lc8;

    f32x4 acc[8][4];
    #pragma unroll
    for (int i = 0; i < 8; ++i)
        #pragma unroll
        for (int j = 0; j < 4; ++j){
            f32x4 z = {0.f,0.f,0.f,0.f};
            acc[i][j] = z;
        }

    auto stage = [&](int kt, int bufn){
        int tap = kt >> 3;
        int c0  = (kt & 7) << 5;
        int kh  = tap / 3, kw = tap - kh*3;
        const u16* a0 = aS + tap*CIN + c0;
        const u16* b0 = bS + (kh*HP + kw)*CIN + c0;
        u16* base = lds + bufn*16384 + w*512;
        gload(a0, base);
        gload(a0 + (size_t)128*9*CIN, base + 4096);
        gload(b0, base + 8192);
        gload(b0 + (size_t)2*HP*CIN, base + 12288);
    };

    stage(0, 0);
    stage(1, 1);
    stage(2, 2);                 // 12 loads in flight

    for (int kt = 0; kt < NKT2; ++kt){
        if (kt < NKT2-2)       asm volatile("s_waitcnt vmcnt(8)" ::: "memory");
        else if (kt == NKT2-2) asm volatile("s_waitcnt vmcnt(4)" ::: "memory");
        else                   asm volatile("s_waitcnt vmcnt(0)" ::: "memory");
        __builtin_amdgcn_s_barrier();

        int bc = kt & 3;
        const u16* LA = lds + bc*16384;
        const u16* LB = LA + 8192;

        bf16x8 af[8], bfv[4];
        #pragma unroll
        for (int mf = 0; mf < 8; ++mf)
            af[mf] = *(const bf16x8*)(LA + (wm + mf*16 + l16)*32 + ck);
        #pragma unroll
        for (int nf = 0; nf < 4; ++nf)
            bfv[nf] = *(const bf16x8*)(LB + (wn + nf*16 + l16)*32 + ck);

        if (kt + 3 < NKT2) stage(kt + 3, (kt + 3) & 3);

        asm volatile("s_waitcnt lgkmcnt(0)" ::: "memory");
        __builtin_amdgcn_sched_barrier(0);   // rule #18

        __builtin_amdgcn_s_setprio(1);
        #pragma unroll
        for (int mf = 0; mf < 8; ++mf)
            #pragma unroll
            for (int nf = 0; nf < 4; ++nf)
                acc[mf][nf] = __builtin_amdgcn_mfma_f32_16x16x32_bf16(
                    af[mf], bfv[nf], acc[mf][nf], 0, 0, 0);
        __builtin_amdgcn_s_setprio(0);
    }

    const float* ab = aggb + b*COUT;
    float* outp = out + ((size_t)b*COUT)*NPIX + nt*256;
    #pragma unroll
    for (int mf = 0; mf < 8; ++mf){
        #pragma unroll
        for (int v = 0; v < 4; ++v){
            int r = wm + mf*16 + kh4*4 + v;
            float bias_r = ab[r];
            float* orow = outp + (size_t)r*NPIX;
            #pragma unroll
            for (int nf = 0; nf < 4; ++nf)
                orow[wn + nf*16 + l16] = acc[mf][nf][v] + bias_r;
        }
    }
}

extern "C" void kernel_launch(void* const* d_in, const int* in_sizes, int n_in,
                              void* d_out, int out_size, void* d_ws, size_t ws_size,
                              hipStream_t stream)
{
    const float* x      = (const float*)d_in[0];
    const float* weight = (const float*)d_in[1];
    const float* bias   = (const float*)d_in[2];
    const float* rw     = (const float*)d_in[3];
    const float* rb     = (const float*)d_in[4];
    float* out = (float*)d_out;

    char* ws = (char*)d_ws;
    u16*   aggw    = (u16*)(ws);                          // 18,874,368 B
    u16*   xt2     = (u16*)(ws + 18874368);               // 35,684,352 B (halo 66x66)
    float* pooled  = (float*)(ws + 54558720);             // 16 KB
    float* aggb    = (float*)(ws + 54558720 + 16384);     // 16 KB

    k_zero <<<520,  256, 0, stream>>>(xt2, pooled);
    k_xt   <<<4096, 256, 0, stream>>>(x, xt2, pooled);
    k_aggw <<<COUT, 256, 0, stream>>>(weight, pooled, rw, rb, bias, aggw, aggb);
    k_conv <<<256,  512, 0, stream>>>(aggw, xt2, aggb, out);
}

// Round 8
// 145.165 us; speedup vs baseline: 1.0572x; 1.0195x over previous
//
#include <hip/hip_runtime.h>
#include <hip/hip_bf16.h>

typedef unsigned short u16;
typedef __attribute__((ext_vector_type(8))) short bf16x8;
typedef __attribute__((ext_vector_type(4))) float f32x4;

#define B_ 16
#define CIN 256
#define COUT 256
#define NPIX 4096
#define E_ 8
#define HP 66            // halo-padded width/height
#define PPIX (HP*HP)     // 4356 padded pixels per sample
#define KTOT 2304        // 9 * 256
#define NKT 36           // K-tiles of 64

__device__ __forceinline__ u16 f2bf(float f){
    union { float f; unsigned int u; } v; v.f = f;
    return (u16)((v.u + 0x7FFFu + ((v.u >> 16) & 1u)) >> 16);
}

__device__ __forceinline__ void gload(const u16* g, u16* l){
    __builtin_amdgcn_global_load_lds(
        (const __attribute__((address_space(1))) unsigned int*)g,
        (__attribute__((address_space(3))) unsigned int*)l, 16, 0, 0);
}

// -------- 0) zero halo borders of xt2 + zero pooled --------
__global__ void k_zero(u16* __restrict__ xt2, float* __restrict__ pooled){
    int gid = blockIdx.x*256 + threadIdx.x;
    if (gid < B_*CIN) pooled[gid] = 0.f;
    int u4 = gid & 31;
    int pl = gid >> 5;
    if (pl >= B_*260) return;
    int b = pl / 260;
    int pi = pl - b*260;
    int y, x;
    if (pi < 66)      { y = 0;  x = pi; }
    else if (pi < 132){ y = 65; x = pi - 66; }
    else { int q = pi - 132; y = 1 + (q >> 1); x = (q & 1) ? 65 : 0; }
    uint4 z = {0u,0u,0u,0u};
    *(uint4*)(xt2 + ((size_t)b*PPIX + y*HP + x)*CIN + u4*8) = z;
}

// -------- 1) transpose+convert x -> xt2[b][(y+1)*66+(x+1)][cin] bf16, fused pool --------
__global__ void k_xt(const float* __restrict__ x, u16* __restrict__ xt2,
                     float* __restrict__ pooled){
    __shared__ float tile[64][65];
    int bid = blockIdx.x;
    int b = bid >> 8, ct = (bid >> 6) & 3, pt = bid & 63;
    int c0 = ct*64, p0 = pt*64, t = threadIdx.x;
    #pragma unroll
    for (int iter = 0; iter < 4; ++iter){
        int idx = t*4 + iter*1024;
        int r = idx >> 6, c4 = idx & 63;
        float4 v = *(const float4*)(x + ((size_t)(b*CIN + c0 + r))*NPIX + p0 + c4);
        tile[r][c4+0] = v.x; tile[r][c4+1] = v.y; tile[r][c4+2] = v.z; tile[r][c4+3] = v.w;
        float rs = v.x + v.y + v.z + v.w;
        #pragma unroll
        for (int off = 1; off < 16; off <<= 1) rs += __shfl_xor(rs, off, 64);
        if ((t & 15) == 0) atomicAdd(&pooled[b*CIN + c0 + r], rs);
    }
    __syncthreads();
    #pragma unroll
    for (int iter = 0; iter < 4; ++iter){
        int idx = t*4 + iter*1024;
        int pr = idx >> 6, cc = idx & 63;
        ushort4 u;
        u.x = f2bf(tile[cc+0][pr]);
        u.y = f2bf(tile[cc+1][pr]);
        u.z = f2bf(tile[cc+2][pr]);
        u.w = f2bf(tile[cc+3][pr]);
        int p = p0 + pr;
        int yy = p >> 6, xx = p & 63;
        *(ushort4*)(xt2 + ((size_t)b*PPIX + (yy+1)*HP + (xx+1))*CIN + c0 + cc) = u;
    }
}

// -------- 2) aggregated weights + fused routing + aggregated bias --------
__global__ void k_aggw(const float* __restrict__ weight, const float* __restrict__ pooled,
                       const float* __restrict__ rw, const float* __restrict__ rb,
                       const float* __restrict__ bias,
                       u16* __restrict__ aggw, float* __restrict__ aggb)
{
    __shared__ float wls[E_][2304];
    __shared__ float r_s[B_*E_];
    int o = blockIdx.x, t = threadIdx.x;

    if (t < B_*E_){
        int b = t >> 3, e = t & 7;
        const float4* pp = (const float4*)(pooled + b*CIN);
        const float4* wp = (const float4*)(rw + e*CIN);
        float s = 0.f;
        #pragma unroll
        for (int i = 0; i < 64; ++i){
            float4 a = pp[i], c = wp[i];
            s += a.x*c.x + a.y*c.y + a.z*c.z + a.w*c.w;
        }
        s = s * (1.0f/(float)NPIX) + rb[e];
        r_s[t] = 1.0f/(1.0f + __expf(-s));
    }
    #pragma unroll
    for (int e = 0; e < E_; ++e){
        const float4* src = (const float4*)(weight + ((size_t)(e*COUT + o))*2304);
        float4* dst = (float4*)wls[e];
        #pragma unroll
        for (int i = 0; i < 3; ++i){
            int idx = t + i*256;
            if (idx < 576) dst[idx] = src[idx];
        }
    }
    __syncthreads();

    if (t < B_){
        float s = 0.f;
        #pragma unroll
        for (int e = 0; e < E_; ++e) s += r_s[t*E_+e]*bias[e*COUT+o];
        aggb[t*COUT + o] = s;
    }

    float w[E_][9];
    #pragma unroll
    for (int e = 0; e < E_; ++e)
        #pragma unroll
        for (int tp = 0; tp < 9; ++tp) w[e][tp] = wls[e][t*9 + tp];
    for (int b = 0; b < B_; ++b){
        float acc[9];
        #pragma unroll
        for (int tp = 0; tp < 9; ++tp) acc[tp] = 0.f;
        #pragma unroll
        for (int e = 0; e < E_; ++e){
            float r = r_s[b*E_+e];
            #pragma unroll
            for (int tp = 0; tp < 9; ++tp) acc[tp] += r*w[e][tp];
        }
        #pragma unroll
        for (int tp = 0; tp < 9; ++tp)
            aggw[(((size_t)(b*COUT + o))*9 + tp)*CIN + t] = f2bf(acc[tp]);
    }
}

// -------- 3) 256x256 tile, BK=64, 8-phase-style schedule (4 phases/K-tile) --------
// LDS: 2 buf x 4 slots (A0,A1,B0,B1) x 16KB = 128KB. Swizzle: granule ^= row&7.
#define BAR() __builtin_amdgcn_s_barrier()
#define LGKM0() do{ asm volatile("s_waitcnt lgkmcnt(0)" ::: "memory"); \
                    __builtin_amdgcn_sched_barrier(0); }while(0)

__global__ __launch_bounds__(512, 1) void k_conv(
    const u16* __restrict__ aggw, const u16* __restrict__ xt2,
    const float* __restrict__ aggb, float* __restrict__ out)
{
    __shared__ __align__(16) u16 lds[65536];

    int orig = blockIdx.x;
    int bid = (orig & 7)*32 + (orig >> 3);   // bijective XCD swizzle (256 % 8 == 0)

    int b  = bid >> 4;
    int nt = bid & 15;
    int y0 = nt << 2;

    int t = threadIdx.x;
    int lane = t & 63;
    int w = t >> 6;
    int wm = (w >> 2) << 7;      // 0 / 128
    int wn = (w & 3) << 6;       // 0 / 64 / 128 / 192
    int l16 = lane & 15;
    int kh4 = lane >> 4;

    // read-side swizzled granule offsets (u16) for khalf 0/1
    int ck0 = ((kh4      ^ (l16 & 7)) << 3);
    int ck1 = (((kh4+4)  ^ (l16 & 7)) << 3);

    // staging: thread t -> row sr = t>>3 (+64*i), granule slot t&7 holds logical granule gl
    int sr = t >> 3;
    int gl8 = (((t & 7) ^ (sr & 7)) << 3);

    const u16* aA = aggw + (size_t)b*COUT*9*CIN + (size_t)sr*(9*CIN) + gl8;
    const u16* bB = xt2 + ((size_t)b*PPIX + (size_t)y0*HP + sr)*CIN + gl8;

    f32x4 acc[8][4];
    #pragma unroll
    for (int i = 0; i < 8; ++i)
        #pragma unroll
        for (int j = 0; j < 4; ++j){
            f32x4 z = {0.f,0.f,0.f,0.f};
            acc[i][j] = z;
        }

    auto stageA = [&](int st, int db, int half){
        int tap = st >> 2, c0 = (st & 3) << 6;
        const u16* s = aA + (size_t)half*128*(9*CIN) + tap*CIN + c0;
        u16* d = lds + db*32768 + half*4096*2 + t*8;         // A slots at 0 / 8192
        gload(s, d);
        gload(s + (size_t)64*(9*CIN), d + 4096);
    };
    auto stageB = [&](int st, int db, int half){
        int tap = st >> 2, c0 = (st & 3) << 6;
        int kh = tap/3, kw = tap - 3*kh;
        const u16* s = bB + ((size_t)(half*2 + kh)*HP + kw)*CIN + c0;
        u16* d = lds + db*32768 + 16384 + half*8192 + t*8;   // B slots at 16384 / 24576
        gload(s, d);
        gload(s + (size_t)HP*CIN, d + 4096);
    };

    // prologue: T0 {B0,B1,A0,A1} -> buf0 ; T1 {B0,B1} -> buf1
    stageB(0,0,0); stageB(0,0,1); stageA(0,0,0); stageA(0,0,1);
    stageB(1,1,0); stageB(1,1,1);
    asm volatile("s_waitcnt vmcnt(4)" ::: "memory");   // T0 landed; T1.B in flight
    BAR();

    int sA = (wm >> 7) << 12;          // *4096 u16 = 8192 B slot stride... (u16 units: 0/4096)
    sA <<= 1;                          // 0 / 8192 u16
    int sB = 16384 + (((wn >> 7) & 1) << 13);
    int cB = wn & 64;

    bf16x8 af0[4][2], af1[4][2], bfv[4][2];

    for (int kt = 0; kt < NKT; ++kt){
        int buf = kt & 1;
        const u16* LA = lds + buf*32768 + sA;
        const u16* LB = lds + buf*32768 + sB;
        int n1 = kt+1 < NKT ? kt+1 : NKT-1;
        int n2 = kt+2 < NKT ? kt+2 : NKT-1;

        // ---- P1: read af0(8) + bfv01(4); stage A0(kt+1); MFMA qm0 x qn0
        #pragma unroll
        for (int mf = 0; mf < 4; ++mf){
            int ro = (mf*16 + l16)*64;
            af0[mf][0] = *(const bf16x8*)(LA + ro + ck0);
            af0[mf][1] = *(const bf16x8*)(LA + ro + ck1);
        }
        #pragma unroll
        for (int nf = 0; nf < 2; ++nf){
            int ro = (cB + nf*16 + l16)*64;
            bfv[nf][0] = *(const bf16x8*)(LB + ro + ck0);
            bfv[nf][1] = *(const bf16x8*)(LB + ro + ck1);
        }
        stageA(n1, buf^1, 0);
        BAR();
        LGKM0();
        __builtin_amdgcn_s_setprio(1);
        #pragma unroll
        for (int mf = 0; mf < 4; ++mf)
            #pragma unroll
            for (int nf = 0; nf < 2; ++nf){
                acc[mf][nf] = __builtin_amdgcn_mfma_f32_16x16x32_bf16(af0[mf][0], bfv[nf][0], acc[mf][nf], 0,0,0);
                acc[mf][nf] = __builtin_amdgcn_mfma_f32_16x16x32_bf16(af0[mf][1], bfv[nf][1], acc[mf][nf], 0,0,0);
            }
        __builtin_amdgcn_s_setprio(0);
        BAR();

        // ---- P2: read bfv23(4); stage A1(kt+1); MFMA qm0 x qn1
        #pragma unroll
        for (int nf = 2; nf < 4; ++nf){
            int ro = (cB + nf*16 + l16)*64;
            bfv[nf][0] = *(const bf16x8*)(LB + ro + ck0);
            bfv[nf][1] = *(const bf16x8*)(LB + ro + ck1);
        }
        stageA(n1, buf^1, 1);
        BAR();
        LGKM0();
        __builtin_amdgcn_s_setprio(1);
        #pragma unroll
        for (int mf = 0; mf < 4; ++mf)
            #pragma unroll
            for (int nf = 2; nf < 4; ++nf){
                acc[mf][nf] = __builtin_amdgcn_mfma_f32_16x16x32_bf16(af0[mf][0], bfv[nf][0], acc[mf][nf], 0,0,0);
                acc[mf][nf] = __builtin_amdgcn_mfma_f32_16x16x32_bf16(af0[mf][1], bfv[nf][1], acc[mf][nf], 0,0,0);
            }
        __builtin_amdgcn_s_setprio(0);
        BAR();

        // ---- P3: read af1(8); stage B0(kt+2); MFMA qm1 x qn0
        #pragma unroll
        for (int mf = 0; mf < 4; ++mf){
            int ro = (64 + mf*16 + l16)*64;
            af1[mf][0] = *(const bf16x8*)(LA + ro + ck0);
            af1[mf][1] = *(const bf16x8*)(LA + ro + ck1);
        }
        stageB(n2, buf, 0);
        BAR();
        LGKM0();
        __builtin_amdgcn_s_setprio(1);
        #pragma unroll
        for (int mf = 0; mf < 4; ++mf)
            #pragma unroll
            for (int nf = 0; nf < 2; ++nf){
                acc[4+mf][nf] = __builtin_amdgcn_mfma_f32_16x16x32_bf16(af1[mf][0], bfv[nf][0], acc[4+mf][nf], 0,0,0);
                acc[4+mf][nf] = __builtin_amdgcn_mfma_f32_16x16x32_bf16(af1[mf][1], bfv[nf][1], acc[4+mf][nf], 0,0,0);
            }
        __builtin_amdgcn_s_setprio(0);
        BAR();

        // ---- P4: stage B1(kt+2); vmcnt(4): tile kt+1 fully landed; MFMA qm1 x qn1
        stageB(n2, buf, 1);
        asm volatile("s_waitcnt vmcnt(4)" ::: "memory");
        BAR();
        __builtin_amdgcn_s_setprio(1);
        #pragma unroll
        for (int mf = 0; mf < 4; ++mf)
            #pragma unroll
            for (int nf = 2; nf < 4; ++nf){
                acc[4+mf][nf] = __builtin_amdgcn_mfma_f32_16x16x32_bf16(af1[mf][0], bfv[nf][0], acc[4+mf][nf], 0,0,0);
                acc[4+mf][nf] = __builtin_amdgcn_mfma_f32_16x16x32_bf16(af1[mf][1], bfv[nf][1], acc[4+mf][nf], 0,0,0);
            }
        __builtin_amdgcn_s_setprio(0);
        BAR();
    }
    asm volatile("s_waitcnt vmcnt(0)" ::: "memory");

    const float* ab = aggb + b*COUT;
    float* outp = out + ((size_t)b*COUT)*NPIX + nt*256;
    #pragma unroll
    for (int mf8 = 0; mf8 < 8; ++mf8){
        #pragma unroll
        for (int v = 0; v < 4; ++v){
            int r = wm + mf8*16 + kh4*4 + v;
            float bias_r = ab[r];
            float* orow = outp + (size_t)r*NPIX;
            #pragma unroll
            for (int nf = 0; nf < 4; ++nf)
                orow[wn + nf*16 + l16] = acc[mf8][nf][v] + bias_r;
        }
    }
}

extern "C" void kernel_launch(void* const* d_in, const int* in_sizes, int n_in,
                              void* d_out, int out_size, void* d_ws, size_t ws_size,
                              hipStream_t stream)
{
    const float* x      = (const float*)d_in[0];
    const float* weight = (const float*)d_in[1];
    const float* bias   = (const float*)d_in[2];
    const float* rw     = (const float*)d_in[3];
    const float* rb     = (const float*)d_in[4];
    float* out = (float*)d_out;

    char* ws = (char*)d_ws;
    u16*   aggw    = (u16*)(ws);                          // 18,874,368 B
    u16*   xt2     = (u16*)(ws + 18874368);               // 35,684,352 B (halo 66x66)
    float* pooled  = (float*)(ws + 54558720);             // 16 KB
    float* aggb    = (float*)(ws + 54558720 + 16384);     // 16 KB

    k_zero <<<520,  256, 0, stream>>>(xt2, pooled);
    k_xt   <<<4096, 256, 0, stream>>>(x, xt2, pooled);
    k_aggw <<<COUT, 256, 0, stream>>>(weight, pooled, rw, rb, bias, aggw, aggb);
    k_conv <<<256,  512, 0, stream>>>(aggw, xt2, aggb, out);
}